// Round 3
// baseline (407.412 us; speedup 1.0000x reference)
//
#include <hip/hip_runtime.h>
#include <stdint.h>

// 3D correlation: x1/x2 (1,32,48,48,48) fp32, D_MAX=4 -> 729 offsets, out fp32 (1,729,48,48,48).
// out[(i*9+j)*9+k][h][w][d] = (1/32) * sum_c x1[c,h,w,d] * x2[c, h+i-4, w+j-4, d+k-4]
//
// R7 vs R6 (192 us kernel): R4 (2 blk/CU, reg-staging, bank-conflicted) == R6
// (3 blk/CU, gload_lds dbuf, conflict-free) == ~190 -> neither occupancy nor
// staging nor latency is the limiter; remaining suspect = LDS instruction
// throughput (6 ds_read_b128 / 72 FMA). R7 cuts ds/FMA by 33% via diagonal
// pairing: outputs (w,j) and (w+1,j-1) share the same x2 window row (w+j const),
// so one thread computes both: 8 ds_read_b128 per 144 FMA. WT=8 (blocks halve,
// half the barriers), 240/256 active lanes. acc 144 -> ~200 VGPR -> 2 blk/CU
// (proven non-penalty). Staging machinery identical to R6.

#define HH 48
#define WW 48
#define DD 48
#define PAD 4
#define OD 9
#define WT 8            // w positions per block
#define PP 8            // d positions per thread
#define CCH 4           // channels per chunk (= #waves; wave wv stages channel wv)
#define NCHUNK 8
#define X2POS 15        // 16B units per staged x2 row (pos 0,13,14 = zero pads)
#define X2ROW 60        // floats per staged x2 row
#define X2W 16          // staged x2 w extent (w0-4 .. w0+11)
#define NACT 240        // 4 q * 10 jp * 6 dg
#define X2UC 240        // x2 16B units per channel (X2W * X2POS)
#define X1UC 96         // x1 16B units per channel (WT*DD/4)
#define X2_FLOATS (CCH * X2W * X2ROW)   // 3840
#define X1_FLOATS (CCH * WT * DD)       // 1536
#define HWD (HH * WW * DD)
#define CHFLOATS (CCH * HWD)

#define GLOAD16(gp, lp)                                                  \
  __builtin_amdgcn_global_load_lds(                                      \
      (const __attribute__((address_space(1))) void*)(gp),               \
      (__attribute__((address_space(3))) void*)(lp), 16, 0, 0)

__global__ __launch_bounds__(256, 2) void corr_kernel(
    const float* __restrict__ x1,
    const float* __restrict__ x2,
    float* __restrict__ out) {

  __shared__ __attribute__((aligned(16))) float s_x2[2][X2_FLOATS]; // 30.7 KB
  __shared__ __attribute__((aligned(16))) float s_x1[2][X1_FLOATS]; // 12.3 KB

  const int wt = blockIdx.x;   // 0..5
  const int h  = blockIdx.y;   // 0..47
  const int i  = blockIdx.z;   // 0..8
  const int w0 = wt * WT;
  const int r  = h + i - PAD;
  const int t  = threadIdx.x;
  const int lane = t & 63;
  const int wv   = t >> 6;     // wave id 0..3 == staged channel within chunk
  const bool row_ok = (r >= 0) & (r < HH);

  // ---- zero both buffers once (pad slots stay 0: masked lanes never write) ----
  {
    const float4 z = make_float4(0.f, 0.f, 0.f, 0.f);
    for (int s = t; s < (2 * X2_FLOATS) / 4; s += 256)
      reinterpret_cast<float4*>(&s_x2[0][0])[s] = z;
    for (int s = t; s < (2 * X1_FLOATS) / 4; s += 256)
      reinterpret_cast<float4*>(&s_x1[0][0])[s] = z;
  }

  // ---- staging decode, chunk-invariant ----
  // x2: wave wv stages channel wv: unit m = u*64+lane (m<240): w=m/15, pos=m%15
  uint32_t o2[4];
  bool m2[4];
#pragma unroll
  for (int u = 0; u < 4; ++u) {
    const int m   = u * 64 + lane;
    const int w   = m / X2POS;
    const int pos = m - w * X2POS;
    const int wg  = w0 + w - PAD;
    m2[u] = (m < X2UC) & row_ok & ((unsigned)wg < (unsigned)WW) &
            ((unsigned)(pos - 1) < 12u);
    o2[u] = (uint32_t)(wv * HWD + r * (WW * DD) + wg * DD + (pos - 1) * 4);
  }
  // x1: wave wv stages channel wv: 96 contiguous 16B units
  uint32_t o1[2];
  bool m1[2];
#pragma unroll
  for (int u = 0; u < 2; ++u) {
    const int m = u * 64 + lane;
    m1[u] = (m < X1UC);
    o1[u] = (uint32_t)(wv * HWD + h * (WW * DD) + w0 * DD + m * 4);
  }

  // exact per-wave global_load_lds count per chunk (for the counted vmcnt wait)
  int nvm = 0;
#pragma unroll
  for (int u = 0; u < 4; ++u) nvm += (__ballot(m2[u]) != 0ull) ? 1 : 0;
#pragma unroll
  for (int u = 0; u < 2; ++u) nvm += (__ballot(m1[u]) != 0ull) ? 1 : 0;

  // ---- compute mapping: t = dg + 6*jp + 60*q ----
  // thread computes outputs A=(w0+2q, j=jp) [jp<=8] and B=(w0+2q+1, j=jp-1) [jp>=1]
  // both use staged x2 row rr = 2q+jp  (w+j == const on the diagonal)
  const bool active = (t < NACT);
  int q = 0, jp = 0, dg = 0;
  if (active) {
    q = t / 60;
    int rem = t - q * 60;
    jp = rem / 6;
    dg = rem - jp * 6;
  }
  const int d0 = dg * PP;
  const int rr = 2 * q + jp;   // 0..15
  const bool validA = active & (jp <= 8);
  const bool validB = active & (jp >= 1);

  float accA[OD][PP], accB[OD][PP];
#pragma unroll
  for (int k = 0; k < OD; ++k)
#pragma unroll
    for (int p = 0; p < PP; ++p) { accA[k][p] = 0.0f; accB[k][p] = 0.0f; }

  __syncthreads();  // zeros visible before any global_load_lds write lands

  // ---- prologue: stage chunk 0 -> buffer 0 ----
#pragma unroll
  for (int u = 0; u < 4; ++u)
    if (m2[u]) GLOAD16(x2 + o2[u], &s_x2[0][(wv * X2UC + u * 64) * 4]);
#pragma unroll
  for (int u = 0; u < 2; ++u)
    if (m1[u]) GLOAD16(x1 + o1[u], &s_x1[0][(wv * X1UC + u * 64) * 4]);

  for (int ch = 0; ch < NCHUNK; ++ch) {
    const int b = ch & 1;
    if (ch + 1 < NCHUNK) {
      const float* g2 = x2 + (size_t)(ch + 1) * CHFLOATS;
      const float* g1 = x1 + (size_t)(ch + 1) * CHFLOATS;
#pragma unroll
      for (int u = 0; u < 4; ++u)
        if (m2[u]) GLOAD16(g2 + o2[u], &s_x2[b ^ 1][(wv * X2UC + u * 64) * 4]);
#pragma unroll
      for (int u = 0; u < 2; ++u)
        if (m1[u]) GLOAD16(g1 + o1[u], &s_x1[b ^ 1][(wv * X1UC + u * 64) * 4]);
      switch (nvm) {  // leave next chunk's nvm loads in flight
        case 6: asm volatile("s_waitcnt vmcnt(6)" ::: "memory"); break;
        case 5: asm volatile("s_waitcnt vmcnt(5)" ::: "memory"); break;
        case 4: asm volatile("s_waitcnt vmcnt(4)" ::: "memory"); break;
        case 3: asm volatile("s_waitcnt vmcnt(3)" ::: "memory"); break;
        case 2: asm volatile("s_waitcnt vmcnt(2)" ::: "memory"); break;
        default: asm volatile("s_waitcnt vmcnt(1)" ::: "memory"); break;
      }
    } else {
      asm volatile("s_waitcnt vmcnt(0)" ::: "memory");
    }
    __builtin_amdgcn_s_barrier();       // all waves' current-chunk loads landed
    __builtin_amdgcn_sched_barrier(0);  // keep LDS reads below the barrier

    if (active) {
#pragma unroll 2
      for (int c = 0; c < CCH; ++c) {
        const float* pw = &s_x2[b][c * (X2W * X2ROW) + rr * X2ROW + d0];
        float win[PP + 8];
#pragma unroll
        for (int u = 0; u < 4; ++u) {
          const float4 v = *reinterpret_cast<const float4*>(pw + u * 4);
          win[u * 4 + 0] = v.x; win[u * 4 + 1] = v.y;
          win[u * 4 + 2] = v.z; win[u * 4 + 3] = v.w;
        }
        const float* pa = &s_x1[b][c * (WT * DD) + (2 * q) * DD + d0];
        float xvA[PP], xvB[PP];
#pragma unroll
        for (int u = 0; u < 2; ++u) {
          const float4 va = *reinterpret_cast<const float4*>(pa + u * 4);
          xvA[u * 4 + 0] = va.x; xvA[u * 4 + 1] = va.y;
          xvA[u * 4 + 2] = va.z; xvA[u * 4 + 3] = va.w;
          const float4 vb = *reinterpret_cast<const float4*>(pa + DD + u * 4);
          xvB[u * 4 + 0] = vb.x; xvB[u * 4 + 1] = vb.y;
          xvB[u * 4 + 2] = vb.z; xvB[u * 4 + 3] = vb.w;
        }
#pragma unroll
        for (int k = 0; k < OD; ++k)
#pragma unroll
          for (int p = 0; p < PP; ++p) {
            accA[k][p] = fmaf(xvA[p], win[p + k], accA[k][p]);
            accB[k][p] = fmaf(xvB[p], win[p + k], accB[k][p]);
          }
      }
    }
    __builtin_amdgcn_sched_barrier(0);  // keep reads above barrier2
    __builtin_amdgcn_s_barrier();       // buffer b free for ch+2's loads
    __builtin_amdgcn_sched_barrier(0);  // keep next issue below barrier2
  }

  const float inv = 1.0f / 32.0f;
  if (validA) {
    const size_t spat = ((size_t)h * WW + (w0 + 2 * q)) * DD + d0;
#pragma unroll
    for (int k = 0; k < OD; ++k) {
      const int o = (i * OD + jp) * OD + k;
      float4 lo = make_float4(accA[k][0] * inv, accA[k][1] * inv,
                              accA[k][2] * inv, accA[k][3] * inv);
      float4 hi = make_float4(accA[k][4] * inv, accA[k][5] * inv,
                              accA[k][6] * inv, accA[k][7] * inv);
      float* dst = out + (size_t)o * HWD + spat;
      *reinterpret_cast<float4*>(dst)     = lo;
      *reinterpret_cast<float4*>(dst + 4) = hi;
    }
  }
  if (validB) {
    const size_t spat = ((size_t)h * WW + (w0 + 2 * q + 1)) * DD + d0;
#pragma unroll
    for (int k = 0; k < OD; ++k) {
      const int o = (i * OD + (jp - 1)) * OD + k;
      float4 lo = make_float4(accB[k][0] * inv, accB[k][1] * inv,
                              accB[k][2] * inv, accB[k][3] * inv);
      float4 hi = make_float4(accB[k][4] * inv, accB[k][5] * inv,
                              accB[k][6] * inv, accB[k][7] * inv);
      float* dst = out + (size_t)o * HWD + spat;
      *reinterpret_cast<float4*>(dst)     = lo;
      *reinterpret_cast<float4*>(dst + 4) = hi;
    }
  }
}

extern "C" void kernel_launch(void* const* d_in, const int* in_sizes, int n_in,
                              void* d_out, int out_size, void* d_ws, size_t ws_size,
                              hipStream_t stream) {
  const float* x1 = (const float*)d_in[0];
  const float* x2 = (const float*)d_in[1];
  float* out = (float*)d_out;
  dim3 grid(WW / WT, HH, OD);  // (6, 48, 9)
  corr_kernel<<<grid, 256, 0, stream>>>(x1, x2, out);
}